// Round 1
// baseline (304.534 us; speedup 1.0000x reference)
//
#include <hip/hip_runtime.h>
#include <stdint.h>

#define NB 8
#define F_IN 6300
#define NT 500
#define HID 32
#define NOUT 20
#define NW 99   // u64 mask words per (b,t) row: ceil(6300/64)
#define NWD 8   // u64 words per (b,f) packed time row: ceil(500/64)

// float32 constants, rounded exactly as np.float32 would round the doubles
#define D_SR   0.7788007830714049f     // exp(-1/4)
#define S_SR   0.6795704571147613f     // e/4
#define D_REF  0.36787944117144233f    // exp(-1)
#define C_REF  -5.43656365691809f      // -2*e

#define NROWB ((NB * F_IN) / 4)        // 12600 pack blocks (4 rows each)

// ---------------- K0: pack x into time-bitmasks (binary input!) + transpose w1 ----------------
// x is exactly {0.0f, 1.0f}; packing to bits is lossless. 100.8 MB -> 3.2 MB so the
// low-occupancy serial kernel K1 no longer has to stream HBM at 0.77 waves/SIMD.
__global__ __launch_bounds__(256) void k0_pack(const float* __restrict__ x,
                                               const float* __restrict__ w1,
                                               uint64_t* __restrict__ xb,
                                               float* __restrict__ w1t) {
  const int bid = blockIdx.x;
  const int tid = threadIdx.x;
  if (bid < NROWB) {
    // 4 (b,f) rows per block, one wave each; word k bit j <-> t = 64k + j
    const int row = bid * 4 + (tid >> 6);      // row = b*F_IN + f
    const int lane = tid & 63;
    const float* xr = x + (size_t)row * NT;
    uint64_t m[8];
#pragma unroll
    for (int k = 0; k < 8; k++) {
      int t = k * 64 + lane;
      float v = (t < NT) ? xr[t] : 0.f;        // coalesced 256B per wave per k
      m[k] = __ballot(v > 0.5f);
    }
    if (lane == 0) {
      uint64_t* dst = xb + (size_t)row * NWD;
#pragma unroll
      for (int k = 0; k < 8; k++) dst[k] = m[k];
    }
    return;
  }
  // ---- transpose w1 [32][6300] -> w1t [6300][32] (old k0, fused to save a node) ----
  __shared__ float tl[64][33];
  const int f0 = (bid - NROWB) * 64;
  const int r = tid & 63, g = tid >> 6;
#pragma unroll
  for (int oo = 0; oo < 32; oo += 4) {
    int o = oo + g;
    int f = f0 + r;
    tl[r][o] = (f < F_IN) ? w1[o * F_IN + f] : 0.f;
  }
  __syncthreads();
#pragma unroll
  for (int k = 0; k < 8; k++) {
    int idx = k * 256 + tid;
    int rr = idx >> 5, cc = idx & 31;
    int f = f0 + rr;
    if (f < F_IN) w1t[(size_t)f * 32 + cc] = tl[rr][cc];
  }
}

// ---------------- K1: layer 1 (psp -> spike) from packed bits, exact-order f32 ----------------
// One wave per (b, 64-f word). Per lane: 64 B of bitmask input (vs 2 KB of floats before).
// Exactness: xi,s in {0,1}; fl(a+0)=a for a>=0, and the spike branch fadd(fmul(D,z),1.0f)
// is literally the reference rounding, so the select form is bit-identical.
__global__ __launch_bounds__(64, 1) void k1_layer1(const uint64_t* __restrict__ xb,
                                                   uint64_t* __restrict__ masks) {
  const int wi = blockIdx.x;
  const int b  = blockIdx.y;
  const int lane = threadIdx.x;
  const int f = wi * 64 + lane;
  const uint64_t vmask = __ballot(f < F_IN);     // wave-constant validity mask
  const int fc = (f < F_IN) ? f : (F_IN - 1);    // clamp: in-bounds reads; bits masked later
  const uint64_t* xr = xb + ((size_t)b * F_IN + fc) * NWD;
  uint64_t* mrow = masks + ((size_t)b * NW + wi) * NT;

  float y1 = 0.f, z1 = 0.f, yr = 0.f, zr = 0.f;
  uint64_t wcur = xr[0];

#pragma unroll 1
  for (int gg = 0; gg < 8; gg++) {
    const int gn = (gg < 7) ? gg + 1 : 7;        // stay in-bounds on last group
    uint64_t wnxt = xr[gn];                      // issued early; hidden under 64 steps
    const uint32_t wlo = (uint32_t)wcur;
    const uint32_t whi = (uint32_t)(wcur >> 32);
    uint64_t keep = 0;
#pragma unroll
    for (int j = 0; j < 64; j++) {               // g=7: bits j>=52 are 0 (harmless extra steps)
      const uint32_t bw = (j < 32) ? wlo : whi;
      const bool xbit = ((bw >> (j & 31)) & 1u) != 0u;
      float zm = __fmul_rn(D_SR, z1);
      y1 = __fmul_rn(D_SR, __fadd_rn(y1, z1));          // y = d*(y+z), old z
      z1 = xbit ? __fadd_rn(zm, 1.0f) : zm;             // z = d*z + x, x in {0,1}
      float p = __fmul_rn(S_SR, y1);
      yr = __fmul_rn(D_REF, __fadd_rn(yr, zr));         // refractory alpha state, old zr
      float u = __fadd_rn(p, __fmul_rn(C_REF, yr));
      bool s = (u >= 1.0f);
      float zrm = __fmul_rn(D_REF, zr);
      zr = s ? __fadd_rn(zrm, 1.0f) : zrm;              // zr = d*zr + s
      uint64_t mball = __ballot(s);
      if (lane == j) keep = mball;
    }
    uint64_t* mp = mrow + gg * 64;
    if (gg < 7)                 mp[lane] = keep & vmask;
    else if (lane < NT - 7*64)  mp[lane] = keep & vmask;   // 52 valid t in last group
    wcur = wnxt;
  }
}

// ---------------- K2: sparse fc1: R[b,o,t] = sum_{f active} w1t[f][o] (f64) ----------------
__global__ __launch_bounds__(512) void k2_fc1(const float* __restrict__ w1t,
                                              const uint64_t* __restrict__ masks,
                                              double* __restrict__ R) {
  __shared__ double part[8][32];
  const int tid = threadIdx.x;
  const int wv = tid >> 6;
  const int lane = tid & 63;
  const int half = lane >> 5;
  const int o = lane & 31;
  const int b = blockIdx.x;
  const int t = blockIdx.y * 4 + (wv & 3);
  const int seg = wv >> 2;
  const int wbeg = seg * 50, wend = seg ? NW : 50;
  const uint64_t* mbase = masks + (size_t)b * NW * NT + t;
  const char* wrow = (const char*)w1t + o * 4;
  double acc0 = 0.0, acc1 = 0.0, acc2 = 0.0, acc3 = 0.0;

  int wi = wbeg + half;
  uint64_t mcur = (wi < wend) ? mbase[(size_t)wi * NT] : 0;
  for (; wi < wend; wi += 2) {
    uint64_t mnext = (wi + 2 < wend) ? mbase[(size_t)(wi + 2) * NT] : 0;
    const uint32_t base0 = ((uint32_t)wi << 13);
    uint32_t w = (uint32_t)mcur;
    uint32_t boff = base0;
#pragma unroll
    for (int sub = 0; sub < 2; sub++) {
      while (w) {
        uint32_t i0 = __builtin_ctz(w);                 uint32_t w1_ = w & (w - 1);
        uint32_t i1 = w1_ ? __builtin_ctz(w1_) : 0u;    uint32_t w2_ = w1_ ? (w1_ & (w1_ - 1)) : 0u;
        uint32_t i2 = w2_ ? __builtin_ctz(w2_) : 0u;    uint32_t w3_ = w2_ ? (w2_ & (w2_ - 1)) : 0u;
        uint32_t i3 = w3_ ? __builtin_ctz(w3_) : 0u;    w = w3_ ? (w3_ & (w3_ - 1)) : 0u;
        float a0 = *(const float*)(wrow + boff + (i0 << 7));
        float a1 = *(const float*)(wrow + boff + (i1 << 7));
        float a2 = *(const float*)(wrow + boff + (i2 << 7));
        float a3 = *(const float*)(wrow + boff + (i3 << 7));
        a1 = w1_ ? a1 : 0.0f;
        a2 = w2_ ? a2 : 0.0f;
        a3 = w3_ ? a3 : 0.0f;
        acc0 += (double)a0;
        acc1 += (double)a1;
        acc2 += (double)a2;
        acc3 += (double)a3;
      }
      w = (uint32_t)(mcur >> 32);
      boff = base0 + (32u << 7);
    }
    mcur = mnext;
  }
  double acc = (acc0 + acc1) + (acc2 + acc3);
  int hi2 = __shfl_xor(__double2hiint(acc), 32);
  int lo2 = __shfl_xor(__double2loint(acc), 32);
  acc += __hiloint2double(hi2, lo2);
  if (half == 0) part[wv][o] = acc;
  __syncthreads();
  if (wv < 4 && half == 0) {
    double tot = part[wv][o] + part[wv + 4][o];
    R[((size_t)b * HID + o) * NT + t] = tot;
  }
}

// ---------------- fast f64 psp+spike step: speculative-select short chain ----------------
#define SNN_FAST_STEP(rin, EMIT)                                                \
  {                                                                             \
    y2 = __builtin_fma(dsr, y2, w);          /* y2_t */                         \
    z2 = __builtin_fma(dsr, z2, (rin));      /* z2_t */                         \
    w  = dsr * z2;                                                              \
    double p  = ssr * y2;                                                       \
    double u0 = __builtin_fma(cr, q, p);                                        \
    double u1 = u0 + K;                                                         \
    double u  = sp ? u1 : u0;                                                   \
    bool s = (u >= 1.0);                                                        \
    double yr = q + (sp ? dre : 0.0);        /* yr_t */                         \
    double zr = zrd + (sp ? 1.0 : 0.0);      /* zr_{t-1} */                     \
    zrd = dre * zr;                                                             \
    q = __builtin_fma(dre, yr, dre * zrd);   /* q_t */                          \
    sp = s;                                                                     \
    EMIT                                                                        \
  }

// ---------------- K3: layer-2 psp+spike -> s2m[b][t] uint32 bitmask ----------------
__global__ __launch_bounds__(64) void k3_spike2(const double* __restrict__ R,
                                                uint32_t* __restrict__ s2m) {
  const int blk = blockIdx.x;
  const int lane = threadIdx.x;
  const int half = lane >> 5;
  const int b = blk * 2 + half;
  const int h = lane & 31;
  const double2* r2 = (const double2*)(R + ((size_t)b * HID + h) * NT);
  uint32_t* m0 = s2m + (size_t)(blk * 2) * NT;
  uint32_t* m1 = s2m + (size_t)(blk * 2 + 1) * NT;

  const double dsr = (double)D_SR, ssr = (double)S_SR;
  const double dre = (double)D_REF, cr = (double)C_REF;
  const double K = cr * dre;
  double y2 = 0, z2 = 0, w = 0, q = 0, zrd = 0;
  bool sp = false;

  double2 bufa[8], bufb[8];
#pragma unroll
  for (int i = 0; i < 8; i++) { bufa[i] = r2[i * 2]; bufb[i] = r2[i * 2 + 1]; }

  for (int g8 = 0; g8 < 16; g8++) {
#pragma unroll
    for (int j = 0; j < 8; j++) {
      const int g = g8 * 8 + j;
      if (g >= 125) break;
      const int t = g * 4;
      double2 va = bufa[j], vb = bufb[j];
      SNN_FAST_STEP(va.x, { uint64_t m = __ballot(s);
        if (lane == 0) { m0[t] = (uint32_t)m; m1[t] = (uint32_t)(m >> 32); } })
      SNN_FAST_STEP(va.y, { uint64_t m = __ballot(s);
        if (lane == 0) { m0[t + 1] = (uint32_t)m; m1[t + 1] = (uint32_t)(m >> 32); } })
      SNN_FAST_STEP(vb.x, { uint64_t m = __ballot(s);
        if (lane == 0) { m0[t + 2] = (uint32_t)m; m1[t + 2] = (uint32_t)(m >> 32); } })
      SNN_FAST_STEP(vb.y, { uint64_t m = __ballot(s);
        if (lane == 0) { m0[t + 3] = (uint32_t)m; m1[t + 3] = (uint32_t)(m >> 32); } })
      if (g + 8 < 125) { bufa[j] = r2[(g + 8) * 2]; bufb[j] = r2[(g + 8) * 2 + 1]; }
    }
  }
}

// ---------------- K4: R3[b,o,t] = sum_h w2[o,h]*s2[t,h] via mask (f64, asc h) ----------------
__global__ __launch_bounds__(256) void k4_fc2(const float* __restrict__ w2,
                                              const uint32_t* __restrict__ s2m,
                                              double* __restrict__ R3) {
  __shared__ float w2l[NOUT * HID];
  const int tid = threadIdx.x;
  for (int i = tid; i < NOUT * HID; i += 256) w2l[i] = w2[i];
  __syncthreads();
  int id = blockIdx.x * 256 + tid;
  if (id >= NB * NOUT * NT) return;
  int t = id % NT;
  int bo = id / NT;
  int o = bo % NOUT;
  int b = bo / NOUT;
  uint32_t m = s2m[(size_t)b * NT + t];
  const float* wr = w2l + o * HID;
  double acc = 0.0;
  while (m) {
    uint32_t i0 = __builtin_ctz(m);                 uint32_t m1_ = m & (m - 1);
    uint32_t i1 = m1_ ? __builtin_ctz(m1_) : 0u;    uint32_t m2_ = m1_ ? (m1_ & (m1_ - 1)) : 0u;
    uint32_t i2 = m2_ ? __builtin_ctz(m2_) : 0u;    uint32_t m3_ = m2_ ? (m2_ & (m2_ - 1)) : 0u;
    uint32_t i3 = m3_ ? __builtin_ctz(m3_) : 0u;    m = m3_ ? (m3_ & (m3_ - 1)) : 0u;
    float a0 = wr[i0];
    float a1 = m1_ ? wr[i1] : 0.0f;
    float a2 = m2_ ? wr[i2] : 0.0f;
    float a3 = m3_ ? wr[i3] : 0.0f;
    acc += (double)a0;
    acc += (double)a1;
    acc += (double)a2;
    acc += (double)a3;
  }
  R3[id] = acc;   // [b][o][t] coalesced
}

// ---------------- K5: layer-3 psp+spike -> output f32 [b,o,t] ----------------
__global__ __launch_bounds__(64) void k5_out(const double* __restrict__ R3,
                                             float* __restrict__ out) {
  int id = blockIdx.x * 64 + threadIdx.x;
  if (id >= NB * NOUT) return;
  const double2* r2 = (const double2*)(R3 + (size_t)id * NT);
  float* orow = out + (size_t)id * NT;

  const double dsr = (double)D_SR, ssr = (double)S_SR;
  const double dre = (double)D_REF, cr = (double)C_REF;
  const double K = cr * dre;
  double y2 = 0, z2 = 0, w = 0, q = 0, zrd = 0;
  bool sp = false;

  double2 bufa[8], bufb[8];
#pragma unroll
  for (int i = 0; i < 8; i++) { bufa[i] = r2[i * 2]; bufb[i] = r2[i * 2 + 1]; }

  for (int g8 = 0; g8 < 16; g8++) {
#pragma unroll
    for (int j = 0; j < 8; j++) {
      const int g = g8 * 8 + j;
      if (g >= 125) break;
      double2 va = bufa[j], vb = bufb[j];
      float4 ov;
      SNN_FAST_STEP(va.x, { ov.x = s ? 1.0f : 0.0f; })
      SNN_FAST_STEP(va.y, { ov.y = s ? 1.0f : 0.0f; })
      SNN_FAST_STEP(vb.x, { ov.z = s ? 1.0f : 0.0f; })
      SNN_FAST_STEP(vb.y, { ov.w = s ? 1.0f : 0.0f; })
      *(float4*)(orow + g * 4) = ov;
      if (g + 8 < 125) { bufa[j] = r2[(g + 8) * 2]; bufb[j] = r2[(g + 8) * 2 + 1]; }
    }
  }
}

extern "C" void kernel_launch(void* const* d_in, const int* in_sizes, int n_in,
                              void* d_out, int out_size, void* d_ws, size_t ws_size,
                              hipStream_t stream) {
  const float* x  = (const float*)d_in[0];   // [8,6300,500]
  const float* w1 = (const float*)d_in[1];   // [32,6300]
  const float* w2 = (const float*)d_in[2];   // [20,32]
  float* out = (float*)d_out;                // [8,20,500]

  uint8_t* ws = (uint8_t*)d_ws;
  const size_t W1T_BYTES  = (size_t)F_IN * HID * 4;        //   806,400
  const size_t XBF_BYTES  = (size_t)NB * F_IN * NWD * 8;   // 3,225,600
  const size_t MASK_BYTES = (size_t)NB * NW * NT * 8;      // 3,168,000
  const size_t R_BYTES    = (size_t)NB * HID * NT * 8;     // 1,024,000
  const size_t S2M_BYTES  = (size_t)NB * NT * 4;           //    16,000
  float*    w1t   = (float*)ws;
  uint64_t* xbF   = (uint64_t*)(ws + W1T_BYTES);
  uint64_t* masks = (uint64_t*)(ws + W1T_BYTES + XBF_BYTES);
  double*   R     = (double*)(ws + W1T_BYTES + XBF_BYTES + MASK_BYTES);
  uint32_t* s2m   = (uint32_t*)(ws + W1T_BYTES + XBF_BYTES + MASK_BYTES + R_BYTES);
  double*   R3    = (double*)(ws + W1T_BYTES + XBF_BYTES + MASK_BYTES + R_BYTES + S2M_BYTES);

  k0_pack<<<NROWB + 99, 256, 0, stream>>>(x, w1, xbF, w1t);
  k1_layer1<<<dim3(NW, NB), 64, 0, stream>>>(xbF, masks);
  k2_fc1<<<dim3(NB, NT / 4), 512, 0, stream>>>(w1t, masks, R);
  k3_spike2<<<4, 64, 0, stream>>>(R, s2m);
  k4_fc2<<<(NB * NOUT * NT + 255) / 256, 256, 0, stream>>>(w2, s2m, R3);
  k5_out<<<3, 64, 0, stream>>>(R3, out);
}

// Round 2
// 292.728 us; speedup vs baseline: 1.0403x; 1.0403x over previous
//
#include <hip/hip_runtime.h>
#include <stdint.h>

#define NB 8
#define F_IN 6300
#define NT 500
#define HID 32
#define NOUT 20
#define NW 99   // u64 mask words per (b,t) row: ceil(6300/64)
#define NWD 8   // u64 words per (b,f) packed time row: ceil(500/64)

// float32 constants, rounded exactly as np.float32 would round the doubles
#define D_SR   0.7788007830714049f     // exp(-1/4)
#define S_SR   0.6795704571147613f     // e/4
#define D_REF  0.36787944117144233f    // exp(-1)
#define C_REF  -5.43656365691809f      // -2*e

#define NROWB ((NB * F_IN) / 4)        // 12600 pack blocks (4 rows each)

// ---------------- K0: pack x into time-bitmasks (binary input!) + transpose w1 ----------------
__global__ __launch_bounds__(256) void k0_pack(const float* __restrict__ x,
                                               const float* __restrict__ w1,
                                               uint64_t* __restrict__ xb,
                                               float* __restrict__ w1t) {
  const int bid = blockIdx.x;
  const int tid = threadIdx.x;
  if (bid < NROWB) {
    const int row = bid * 4 + (tid >> 6);      // row = b*F_IN + f
    const int lane = tid & 63;
    const float* xr = x + (size_t)row * NT;
    uint64_t m[8];
#pragma unroll
    for (int k = 0; k < 8; k++) {
      int t = k * 64 + lane;
      float v = (t < NT) ? xr[t] : 0.f;
      m[k] = __ballot(v > 0.5f);
    }
    if (lane == 0) {
      uint64_t* dst = xb + (size_t)row * NWD;
#pragma unroll
      for (int k = 0; k < 8; k++) dst[k] = m[k];
    }
    return;
  }
  // ---- transpose w1 [32][6300] -> w1t [6300][32] ----
  __shared__ float tl[64][33];
  const int f0 = (bid - NROWB) * 64;
  const int r = tid & 63, g = tid >> 6;
#pragma unroll
  for (int oo = 0; oo < 32; oo += 4) {
    int o = oo + g;
    int f = f0 + r;
    tl[r][o] = (f < F_IN) ? w1[o * F_IN + f] : 0.f;
  }
  __syncthreads();
#pragma unroll
  for (int k = 0; k < 8; k++) {
    int idx = k * 256 + tid;
    int rr = idx >> 5, cc = idx & 31;
    int f = f0 + rr;
    if (f < F_IN) w1t[(size_t)f * 32 + cc] = tl[rr][cc];
  }
}

// ---------------- K1: layer 1 (psp -> spike) from packed bits, exact-order f32 ----------------
__global__ __launch_bounds__(64, 1) void k1_layer1(const uint64_t* __restrict__ xb,
                                                   uint64_t* __restrict__ masks) {
  const int wi = blockIdx.x;
  const int b  = blockIdx.y;
  const int lane = threadIdx.x;
  const int f = wi * 64 + lane;
  const uint64_t vmask = __ballot(f < F_IN);
  const int fc = (f < F_IN) ? f : (F_IN - 1);
  const uint64_t* xr = xb + ((size_t)b * F_IN + fc) * NWD;
  uint64_t* mrow = masks + ((size_t)b * NW + wi) * NT;

  float y1 = 0.f, z1 = 0.f, yr = 0.f, zr = 0.f;
  uint64_t wcur = xr[0];

#pragma unroll 1
  for (int gg = 0; gg < 8; gg++) {
    const int gn = (gg < 7) ? gg + 1 : 7;
    uint64_t wnxt = xr[gn];
    const uint32_t wlo = (uint32_t)wcur;
    const uint32_t whi = (uint32_t)(wcur >> 32);
    uint64_t keep = 0;
#pragma unroll
    for (int j = 0; j < 64; j++) {
      const uint32_t bw = (j < 32) ? wlo : whi;
      const bool xbit = ((bw >> (j & 31)) & 1u) != 0u;
      float zm = __fmul_rn(D_SR, z1);
      y1 = __fmul_rn(D_SR, __fadd_rn(y1, z1));
      z1 = xbit ? __fadd_rn(zm, 1.0f) : zm;
      float p = __fmul_rn(S_SR, y1);
      yr = __fmul_rn(D_REF, __fadd_rn(yr, zr));
      float u = __fadd_rn(p, __fmul_rn(C_REF, yr));
      bool s = (u >= 1.0f);
      float zrm = __fmul_rn(D_REF, zr);
      zr = s ? __fadd_rn(zrm, 1.0f) : zrm;
      uint64_t mball = __ballot(s);
      if (lane == j) keep = mball;
    }
    uint64_t* mp = mrow + gg * 64;
    if (gg < 7)                 mp[lane] = keep & vmask;
    else if (lane < NT - 7*64)  mp[lane] = keep & vmask;
    wcur = wnxt;
  }
}

// ---------------- K2: sparse fc1: R[b,o,t] = sum_{f active} w1t[f][o] (f64) ----------------
__global__ __launch_bounds__(512) void k2_fc1(const float* __restrict__ w1t,
                                              const uint64_t* __restrict__ masks,
                                              double* __restrict__ R) {
  __shared__ double part[8][32];
  const int tid = threadIdx.x;
  const int wv = tid >> 6;
  const int lane = tid & 63;
  const int half = lane >> 5;
  const int o = lane & 31;
  const int b = blockIdx.x;
  const int t = blockIdx.y * 4 + (wv & 3);
  const int seg = wv >> 2;
  const int wbeg = seg * 50, wend = seg ? NW : 50;
  const uint64_t* mbase = masks + (size_t)b * NW * NT + t;
  const char* wrow = (const char*)w1t + o * 4;
  double acc0 = 0.0, acc1 = 0.0, acc2 = 0.0, acc3 = 0.0;

  int wi = wbeg + half;
  uint64_t mcur = (wi < wend) ? mbase[(size_t)wi * NT] : 0;
  for (; wi < wend; wi += 2) {
    uint64_t mnext = (wi + 2 < wend) ? mbase[(size_t)(wi + 2) * NT] : 0;
    const uint32_t base0 = ((uint32_t)wi << 13);
    uint32_t w = (uint32_t)mcur;
    uint32_t boff = base0;
#pragma unroll
    for (int sub = 0; sub < 2; sub++) {
      while (w) {
        uint32_t i0 = __builtin_ctz(w);                 uint32_t w1_ = w & (w - 1);
        uint32_t i1 = w1_ ? __builtin_ctz(w1_) : 0u;    uint32_t w2_ = w1_ ? (w1_ & (w1_ - 1)) : 0u;
        uint32_t i2 = w2_ ? __builtin_ctz(w2_) : 0u;    uint32_t w3_ = w2_ ? (w2_ & (w2_ - 1)) : 0u;
        uint32_t i3 = w3_ ? __builtin_ctz(w3_) : 0u;    w = w3_ ? (w3_ & (w3_ - 1)) : 0u;
        float a0 = *(const float*)(wrow + boff + (i0 << 7));
        float a1 = *(const float*)(wrow + boff + (i1 << 7));
        float a2 = *(const float*)(wrow + boff + (i2 << 7));
        float a3 = *(const float*)(wrow + boff + (i3 << 7));
        a1 = w1_ ? a1 : 0.0f;
        a2 = w2_ ? a2 : 0.0f;
        a3 = w3_ ? a3 : 0.0f;
        acc0 += (double)a0;
        acc1 += (double)a1;
        acc2 += (double)a2;
        acc3 += (double)a3;
      }
      w = (uint32_t)(mcur >> 32);
      boff = base0 + (32u << 7);
    }
    mcur = mnext;
  }
  double acc = (acc0 + acc1) + (acc2 + acc3);
  int hi2 = __shfl_xor(__double2hiint(acc), 32);
  int lo2 = __shfl_xor(__double2loint(acc), 32);
  acc += __hiloint2double(hi2, lo2);
  if (half == 0) part[wv][o] = acc;
  __syncthreads();
  if (wv < 4 && half == 0) {
    double tot = part[wv][o] + part[wv + 4][o];
    R[((size_t)b * HID + o) * NT + t] = tot;
  }
}

// ---------------- fast f64 psp+spike step: speculative-select short chain ----------------
#define SNN_FAST_STEP(rin, EMIT)                                                \
  {                                                                             \
    y2 = __builtin_fma(dsr, y2, w);          /* y2_t */                         \
    z2 = __builtin_fma(dsr, z2, (rin));      /* z2_t */                         \
    w  = dsr * z2;                                                              \
    double p  = ssr * y2;                                                       \
    double u0 = __builtin_fma(cr, q, p);                                        \
    double u1 = u0 + K;                                                         \
    double u  = sp ? u1 : u0;                                                   \
    bool s = (u >= 1.0);                                                        \
    double yr = q + (sp ? dre : 0.0);        /* yr_t */                         \
    double zr = zrd + (sp ? 1.0 : 0.0);      /* zr_{t-1} */                     \
    zrd = dre * zr;                                                             \
    q = __builtin_fma(dre, yr, dre * zrd);   /* q_t */                          \
    sp = s;                                                                     \
    EMIT                                                                        \
  }

// 4 steps of one group g, reading from double2 pair (va, vb)
#define K3_GROUP(g, va, vb)                                                     \
  {                                                                             \
    const int t = (g) * 4;                                                      \
    SNN_FAST_STEP(va.x, { uint64_t m = __ballot(s);                             \
      if (lane == 0) { m0[t] = (uint32_t)m; m1[t] = (uint32_t)(m >> 32); } })   \
    SNN_FAST_STEP(va.y, { uint64_t m = __ballot(s);                             \
      if (lane == 0) { m0[t + 1] = (uint32_t)m; m1[t + 1] = (uint32_t)(m >> 32); } }) \
    SNN_FAST_STEP(vb.x, { uint64_t m = __ballot(s);                             \
      if (lane == 0) { m0[t + 2] = (uint32_t)m; m1[t + 2] = (uint32_t)(m >> 32); } }) \
    SNN_FAST_STEP(vb.y, { uint64_t m = __ballot(s);                             \
      if (lane == 0) { m0[t + 3] = (uint32_t)m; m1[t + 3] = (uint32_t)(m >> 32); } }) \
  }

// ---------------- K3: layer-2 psp+spike -> s2m[b][t] uint32 bitmask ----------------
// Ring buffers with STATIC indices only (no break inside unrolled loops): 125 groups
// = 15x8 main + 5 tail. Prefetch uses a clamped index so every load is in-bounds and
// unconditional (3 redundant tail reloads, values unused). Keeps bufs in VGPRs.
__global__ __launch_bounds__(64, 1) void k3_spike2(const double* __restrict__ R,
                                                   uint32_t* __restrict__ s2m) {
  const int blk = blockIdx.x;
  const int lane = threadIdx.x;
  const int half = lane >> 5;
  const int b = blk * 2 + half;
  const int h = lane & 31;
  const double2* r2 = (const double2*)(R + ((size_t)b * HID + h) * NT);
  uint32_t* m0 = s2m + (size_t)(blk * 2) * NT;
  uint32_t* m1 = s2m + (size_t)(blk * 2 + 1) * NT;

  const double dsr = (double)D_SR, ssr = (double)S_SR;
  const double dre = (double)D_REF, cr = (double)C_REF;
  const double K = cr * dre;
  double y2 = 0, z2 = 0, w = 0, q = 0, zrd = 0;
  bool sp = false;

  double2 bufa[8], bufb[8];
#pragma unroll
  for (int i = 0; i < 8; i++) { bufa[i] = r2[i * 2]; bufb[i] = r2[i * 2 + 1]; }

#pragma unroll 1
  for (int g8 = 0; g8 < 15; g8++) {
#pragma unroll
    for (int j = 0; j < 8; j++) {            // constant trip count -> full unroll, j static
      const int g = g8 * 8 + j;              // 0..119
      double2 va = bufa[j], vb = bufb[j];
      int gp = g + 8;                        // prefetch target; (g+8)%8 == j
      if (gp > 124) gp = 124;                // branchless clamp: in-bounds, value unused in tail
      bufa[j] = r2[gp * 2];
      bufb[j] = r2[gp * 2 + 1];
      K3_GROUP(g, va, vb)
    }
  }
#pragma unroll
  for (int j = 0; j < 5; j++) {              // tail groups 120..124, (g%8)==j static
    const int g = 120 + j;
    double2 va = bufa[j], vb = bufb[j];
    K3_GROUP(g, va, vb)
  }
}

// ---------------- K4: R3[b,o,t] = sum_h w2[o,h]*s2[t,h] via mask (f64, asc h) ----------------
__global__ __launch_bounds__(256) void k4_fc2(const float* __restrict__ w2,
                                              const uint32_t* __restrict__ s2m,
                                              double* __restrict__ R3) {
  __shared__ float w2l[NOUT * HID];
  const int tid = threadIdx.x;
  for (int i = tid; i < NOUT * HID; i += 256) w2l[i] = w2[i];
  __syncthreads();
  int id = blockIdx.x * 256 + tid;
  if (id >= NB * NOUT * NT) return;
  int t = id % NT;
  int bo = id / NT;
  int o = bo % NOUT;
  int b = bo / NOUT;
  uint32_t m = s2m[(size_t)b * NT + t];
  const float* wr = w2l + o * HID;
  double acc = 0.0;
  while (m) {
    uint32_t i0 = __builtin_ctz(m);                 uint32_t m1_ = m & (m - 1);
    uint32_t i1 = m1_ ? __builtin_ctz(m1_) : 0u;    uint32_t m2_ = m1_ ? (m1_ & (m1_ - 1)) : 0u;
    uint32_t i2 = m2_ ? __builtin_ctz(m2_) : 0u;    uint32_t m3_ = m2_ ? (m2_ & (m2_ - 1)) : 0u;
    uint32_t i3 = m3_ ? __builtin_ctz(m3_) : 0u;    m = m3_ ? (m3_ & (m3_ - 1)) : 0u;
    float a0 = wr[i0];
    float a1 = m1_ ? wr[i1] : 0.0f;
    float a2 = m2_ ? wr[i2] : 0.0f;
    float a3 = m3_ ? wr[i3] : 0.0f;
    acc += (double)a0;
    acc += (double)a1;
    acc += (double)a2;
    acc += (double)a3;
  }
  R3[id] = acc;   // [b][o][t] coalesced
}

#define K5_GROUP(g, va, vb)                                                     \
  {                                                                             \
    float4 ov;                                                                  \
    SNN_FAST_STEP(va.x, { ov.x = s ? 1.0f : 0.0f; })                            \
    SNN_FAST_STEP(va.y, { ov.y = s ? 1.0f : 0.0f; })                            \
    SNN_FAST_STEP(vb.x, { ov.z = s ? 1.0f : 0.0f; })                            \
    SNN_FAST_STEP(vb.y, { ov.w = s ? 1.0f : 0.0f; })                            \
    *(float4*)(orow + (g) * 4) = ov;                                            \
  }

// ---------------- K5: layer-3 psp+spike -> output f32 [b,o,t] ----------------
__global__ __launch_bounds__(64, 1) void k5_out(const double* __restrict__ R3,
                                                float* __restrict__ out) {
  int id = blockIdx.x * 64 + threadIdx.x;
  if (id >= NB * NOUT) return;
  const double2* r2 = (const double2*)(R3 + (size_t)id * NT);
  float* orow = out + (size_t)id * NT;

  const double dsr = (double)D_SR, ssr = (double)S_SR;
  const double dre = (double)D_REF, cr = (double)C_REF;
  const double K = cr * dre;
  double y2 = 0, z2 = 0, w = 0, q = 0, zrd = 0;
  bool sp = false;

  double2 bufa[8], bufb[8];
#pragma unroll
  for (int i = 0; i < 8; i++) { bufa[i] = r2[i * 2]; bufb[i] = r2[i * 2 + 1]; }

#pragma unroll 1
  for (int g8 = 0; g8 < 15; g8++) {
#pragma unroll
    for (int j = 0; j < 8; j++) {
      const int g = g8 * 8 + j;              // 0..119
      double2 va = bufa[j], vb = bufb[j];
      int gp = g + 8;
      if (gp > 124) gp = 124;
      bufa[j] = r2[gp * 2];
      bufb[j] = r2[gp * 2 + 1];
      K5_GROUP(g, va, vb)
    }
  }
#pragma unroll
  for (int j = 0; j < 5; j++) {
    const int g = 120 + j;
    double2 va = bufa[j], vb = bufb[j];
    K5_GROUP(g, va, vb)
  }
}

extern "C" void kernel_launch(void* const* d_in, const int* in_sizes, int n_in,
                              void* d_out, int out_size, void* d_ws, size_t ws_size,
                              hipStream_t stream) {
  const float* x  = (const float*)d_in[0];   // [8,6300,500]
  const float* w1 = (const float*)d_in[1];   // [32,6300]
  const float* w2 = (const float*)d_in[2];   // [20,32]
  float* out = (float*)d_out;                // [8,20,500]

  uint8_t* ws = (uint8_t*)d_ws;
  const size_t W1T_BYTES  = (size_t)F_IN * HID * 4;        //   806,400
  const size_t XBF_BYTES  = (size_t)NB * F_IN * NWD * 8;   // 3,225,600
  const size_t MASK_BYTES = (size_t)NB * NW * NT * 8;      // 3,168,000
  const size_t R_BYTES    = (size_t)NB * HID * NT * 8;     // 1,024,000
  const size_t S2M_BYTES  = (size_t)NB * NT * 4;           //    16,000
  float*    w1t   = (float*)ws;
  uint64_t* xbF   = (uint64_t*)(ws + W1T_BYTES);
  uint64_t* masks = (uint64_t*)(ws + W1T_BYTES + XBF_BYTES);
  double*   R     = (double*)(ws + W1T_BYTES + XBF_BYTES + MASK_BYTES);
  uint32_t* s2m   = (uint32_t*)(ws + W1T_BYTES + XBF_BYTES + MASK_BYTES + R_BYTES);
  double*   R3    = (double*)(ws + W1T_BYTES + XBF_BYTES + MASK_BYTES + R_BYTES + S2M_BYTES);

  k0_pack<<<NROWB + 99, 256, 0, stream>>>(x, w1, xbF, w1t);
  k1_layer1<<<dim3(NW, NB), 64, 0, stream>>>(xbF, masks);
  k2_fc1<<<dim3(NB, NT / 4), 512, 0, stream>>>(w1t, masks, R);
  k3_spike2<<<4, 64, 0, stream>>>(R, s2m);
  k4_fc2<<<(NB * NOUT * NT + 255) / 256, 256, 0, stream>>>(w2, s2m, R3);
  k5_out<<<3, 64, 0, stream>>>(R3, out);
}